// Round 1
// baseline (140.861 us; speedup 1.0000x reference)
//
#include <hip/hip_runtime.h>

#define BB 4
#define NN 8192      // N == M == 8192
#define TILE 256     // threads per block; one self-point per thread
#define CHUNK 1024   // other-points staged in LDS per block

// Computes, for each point of the "self" cloud, min squared distance over a
// CHUNK of the "other" cloud; combines across chunks with atomicMin on the
// uint bit pattern (valid for non-negative floats).
// dmin layout: [dir][b][8192] as uint bits, dir 0 = d12 (self=p1), 1 = d21.
__global__ __launch_bounds__(TILE) void chamfer_min_kernel(
    const float* __restrict__ p1, const float* __restrict__ p2,
    unsigned* __restrict__ dmin)
{
    const int chunk = blockIdx.x;
    const int tile  = blockIdx.y;
    const int bz    = blockIdx.z;
    const int b   = bz >> 1;
    const int dir = bz & 1;

    const float* self  = dir ? p2 : p1;
    const float* other = dir ? p1 : p2;
    unsigned* out = dmin + (size_t)dir * BB * NN + (size_t)b * NN;

    // Stage CHUNK other-points (CHUNK*3 floats = 12 KB) into LDS, float4 coalesced.
    __shared__ float so[CHUNK * 3];
    {
        const float4* src = reinterpret_cast<const float4*>(
            other + ((size_t)b * NN + (size_t)chunk * CHUNK) * 3);
        float4* dst = reinterpret_cast<float4*>(so);
        #pragma unroll
        for (int i = 0; i < (CHUNK * 3 / 4) / TILE; ++i)
            dst[threadIdx.x + i * TILE] = src[threadIdx.x + i * TILE];
    }
    __syncthreads();

    const int n = tile * TILE + threadIdx.x;
    const float* sp = self + ((size_t)b * NN + n) * 3;
    const float ax = sp[0], ay = sp[1], az = sp[2];

    // 4 independent min accumulators for ILP.
    float m0 = 3.4e38f, m1 = 3.4e38f, m2 = 3.4e38f, m3 = 3.4e38f;

    for (int j = 0; j < CHUNK; j += 4) {
        // 12 floats = 4 points, three aligned float4 broadcast reads from LDS.
        const float4 q0 = *reinterpret_cast<const float4*>(&so[j * 3 + 0]);
        const float4 q1 = *reinterpret_cast<const float4*>(&so[j * 3 + 4]);
        const float4 q2 = *reinterpret_cast<const float4*>(&so[j * 3 + 8]);
        float dx, dy, dz, d;
        dx = ax - q0.x; dy = ay - q0.y; dz = az - q0.z;
        d = fmaf(dx, dx, fmaf(dy, dy, dz * dz)); m0 = fminf(m0, d);
        dx = ax - q0.w; dy = ay - q1.x; dz = az - q1.y;
        d = fmaf(dx, dx, fmaf(dy, dy, dz * dz)); m1 = fminf(m1, d);
        dx = ax - q1.z; dy = ay - q1.w; dz = az - q2.x;
        d = fmaf(dx, dx, fmaf(dy, dy, dz * dz)); m2 = fminf(m2, d);
        dx = ax - q2.y; dy = ay - q2.z; dz = az - q2.w;
        d = fmaf(dx, dx, fmaf(dy, dy, dz * dz)); m3 = fminf(m3, d);
    }

    const float mn = fminf(fminf(m0, m1), fminf(m2, m3));
    atomicMin(&out[n], __float_as_uint(mn));
}

// Since N == M, mean(d12) + mean(d21) = sum(all 2*B*N mins) / (B*N).
__global__ __launch_bounds__(1024) void chamfer_reduce_kernel(
    const unsigned* __restrict__ dmin, float* __restrict__ out)
{
    float s = 0.f;
    for (int i = threadIdx.x; i < 2 * BB * NN; i += 1024)
        s += __uint_as_float(dmin[i]);

    // wave64 tree reduce
    #pragma unroll
    for (int off = 32; off; off >>= 1) s += __shfl_down(s, off);

    __shared__ float wsum[16];
    const int lane = threadIdx.x & 63;
    const int wid  = threadIdx.x >> 6;
    if (lane == 0) wsum[wid] = s;
    __syncthreads();
    if (threadIdx.x == 0) {
        float t = 0.f;
        #pragma unroll
        for (int w = 0; w < 16; ++w) t += wsum[w];
        out[0] = t / (float)(BB * NN);
    }
}

extern "C" void kernel_launch(void* const* d_in, const int* in_sizes, int n_in,
                              void* d_out, int out_size, void* d_ws, size_t ws_size,
                              hipStream_t stream)
{
    const float* p1 = (const float*)d_in[0];
    const float* p2 = (const float*)d_in[1];
    unsigned* dmin  = (unsigned*)d_ws;          // 2*B*N uints = 256 KB
    float* out      = (float*)d_out;

    // 0x7f7f7f7f == 3.39e38f — "infinity" sentinel, valid for uint-min compares.
    hipMemsetAsync(dmin, 0x7f, (size_t)2 * BB * NN * sizeof(unsigned), stream);

    dim3 grid(NN / CHUNK, NN / TILE, BB * 2);   // 8 x 32 x 8 = 2048 blocks
    chamfer_min_kernel<<<grid, TILE, 0, stream>>>(p1, p2, dmin);
    chamfer_reduce_kernel<<<1, 1024, 0, stream>>>(dmin, out);
}

// Round 2
// 109.396 us; speedup vs baseline: 1.2876x; 1.2876x over previous
//
#include <hip/hip_runtime.h>

#define BB 4
#define NN 8192                 // N == M
#define NPTS (BB * NN)          // 32768 points per cloud
#define TILE 256                // threads per block
#define RJ 8                    // j-replicas per self point (lanes tid&7)
#define RI 2                    // self points per thread
#define CHUNK 1024              // other-points staged in LDS per step
#define SELF_PER_BLOCK ((TILE / RJ) * RI)   // 64

// Transform: p [B*N*3] f32 -> t [B*N] float4 = (-2x, -2y, -2z, x^2+y^2+z^2)
__global__ __launch_bounds__(256) void transform_kernel(
    const float* __restrict__ p1, const float* __restrict__ p2,
    float4* __restrict__ t1, float4* __restrict__ t2)
{
    const int i = blockIdx.x * 256 + threadIdx.x;   // 0..NPTS-1
    {
        const float x = p1[3*i], y = p1[3*i+1], z = p1[3*i+2];
        t1[i] = make_float4(-2.f*x, -2.f*y, -2.f*z, fmaf(x,x,fmaf(y,y,z*z)));
    }
    {
        const float x = p2[3*i], y = p2[3*i+1], z = p2[3*i+2];
        t2[i] = make_float4(-2.f*x, -2.f*y, -2.f*z, fmaf(x,x,fmaf(y,y,z*z)));
    }
}

// Fused min+sum. dist^2(i,j) = |a_i|^2 + (|b_j|^2 - 2 a.b) = a2 + v_ij.
// v_ij = fma(ax,qx, fma(ay,qy, fma(az,qz, qw))) with q the transformed other
// point. min_j max(a2+v_ij, 0) = max(a2 + min_j v_ij, 0)  (both monotone).
// Each thread: RI=2 self points, scans 1/RJ of the other cloud (strided within
// each LDS chunk). Partial mins combined across the 8 replica lanes via
// shfl_xor, then block-summed, one atomicAdd per block.
__global__ __launch_bounds__(TILE) void chamfer_main(
    const float* __restrict__ p1, const float* __restrict__ p2,
    const float4* __restrict__ t1, const float4* __restrict__ t2,
    float* __restrict__ out)
{
    const int bz  = blockIdx.y;          // 0..2*BB-1
    const int b   = bz >> 1;
    const int dir = bz & 1;              // 0: self=p1 other=p2 ; 1: self=p2 other=p1
    const float*  selfp  = dir ? p2 : p1;
    const float4* othert = dir ? t1 : t2;

    const int r  = threadIdx.x & (RJ - 1);
    const int g  = threadIdx.x >> 3;                     // 0..31
    const int i0 = blockIdx.x * SELF_PER_BLOCK + g * RI; // self point in [0,NN)

    const float* sp = selfp + ((size_t)b * NN + i0) * 3;
    const float a0x = sp[0], a0y = sp[1], a0z = sp[2];
    const float a1x = sp[3], a1y = sp[4], a1z = sp[5];

    __shared__ float4 so[CHUNK];

    const float INF = 3.4e38f;
    float m0a=INF, m0b=INF, m0c=INF, m0d=INF;   // 4 min chains per self point
    float m1a=INF, m1b=INF, m1c=INF, m1d=INF;

    const float4* src = othert + (size_t)b * NN;

    for (int c = 0; c < NN / CHUNK; ++c) {
        // stage chunk: 1024 float4 = 16 KB, coalesced 16 B/lane
        #pragma unroll
        for (int k = 0; k < CHUNK / TILE; ++k)
            so[threadIdx.x + k * TILE] = src[c * CHUNK + threadIdx.x + k * TILE];
        __syncthreads();

        const float4* bp = &so[r];       // replica stride RJ float4 = 128 B
        #pragma unroll 4
        for (int jj = 0; jj < CHUNK / RJ; jj += 4) {
            const float4 q0 = bp[(jj + 0) * RJ];
            const float4 q1 = bp[(jj + 1) * RJ];
            const float4 q2 = bp[(jj + 2) * RJ];
            const float4 q3 = bp[(jj + 3) * RJ];
            float v;
            v = fmaf(a0x,q0.x, fmaf(a0y,q0.y, fmaf(a0z,q0.z, q0.w))); m0a = fminf(m0a, v);
            v = fmaf(a1x,q0.x, fmaf(a1y,q0.y, fmaf(a1z,q0.z, q0.w))); m1a = fminf(m1a, v);
            v = fmaf(a0x,q1.x, fmaf(a0y,q1.y, fmaf(a0z,q1.z, q1.w))); m0b = fminf(m0b, v);
            v = fmaf(a1x,q1.x, fmaf(a1y,q1.y, fmaf(a1z,q1.z, q1.w))); m1b = fminf(m1b, v);
            v = fmaf(a0x,q2.x, fmaf(a0y,q2.y, fmaf(a0z,q2.z, q2.w))); m0c = fminf(m0c, v);
            v = fmaf(a1x,q2.x, fmaf(a1y,q2.y, fmaf(a1z,q2.z, q2.w))); m1c = fminf(m1c, v);
            v = fmaf(a0x,q3.x, fmaf(a0y,q3.y, fmaf(a0z,q3.z, q3.w))); m0d = fminf(m0d, v);
            v = fmaf(a1x,q3.x, fmaf(a1y,q3.y, fmaf(a1z,q3.z, q3.w))); m1d = fminf(m1d, v);
        }
        __syncthreads();
    }

    float m0 = fminf(fminf(m0a, m0b), fminf(m0c, m0d));
    float m1 = fminf(fminf(m1a, m1b), fminf(m1c, m1d));

    // combine the 8 j-replicas (lanes differing in tid bits 0..2)
    #pragma unroll
    for (int mask = 1; mask < RJ; mask <<= 1) {
        m0 = fminf(m0, __shfl_xor(m0, mask));
        m1 = fminf(m1, __shfl_xor(m1, mask));
    }

    float s = 0.f;
    if (r == 0) {
        const float a2_0 = fmaf(a0x,a0x, fmaf(a0y,a0y, a0z*a0z));
        const float a2_1 = fmaf(a1x,a1x, fmaf(a1y,a1y, a1z*a1z));
        s = fmaxf(m0 + a2_0, 0.f) + fmaxf(m1 + a2_1, 0.f);
    }

    // block sum -> one atomicAdd
    #pragma unroll
    for (int off = 32; off; off >>= 1) s += __shfl_down(s, off);

    __shared__ float wsum[TILE / 64];
    const int lane = threadIdx.x & 63;
    const int wid  = threadIdx.x >> 6;
    if (lane == 0) wsum[wid] = s;
    __syncthreads();
    if (threadIdx.x == 0) {
        float t = 0.f;
        #pragma unroll
        for (int w = 0; w < TILE / 64; ++w) t += wsum[w];
        atomicAdd(out, t * (1.f / (float)NPTS));
    }
}

extern "C" void kernel_launch(void* const* d_in, const int* in_sizes, int n_in,
                              void* d_out, int out_size, void* d_ws, size_t ws_size,
                              hipStream_t stream)
{
    const float* p1 = (const float*)d_in[0];
    const float* p2 = (const float*)d_in[1];
    float4* t1 = (float4*)d_ws;                  // NPTS float4 = 512 KB
    float4* t2 = t1 + NPTS;                      // + 512 KB
    float* out = (float*)d_out;

    hipMemsetAsync(out, 0, sizeof(float), stream);
    transform_kernel<<<NPTS / 256, 256, 0, stream>>>(p1, p2, t1, t2);

    dim3 grid(NN / SELF_PER_BLOCK, BB * 2);      // 128 x 8 = 1024 blocks
    chamfer_main<<<grid, TILE, 0, stream>>>(p1, p2, t1, t2, out);
}